// Round 4
// baseline (367.612 us; speedup 1.0000x reference)
//
#include <hip/hip_runtime.h>
#include <stdint.h>
#include <stddef.h>

// Problem constants (B=4, L=1024, D=768, H=6, DH=128)
#define BB 4
#define LL 1024
#define DD 768
#define HH 6
#define DHH 128
#define EPS 1e-5f

// Inputs fp32, OUTPUTS FP32 (reference returns float32; harness d_out dtype
// follows reference output dtype). Round-2/3 bit-identical 4.718 error was
// my bf16-packed Vh read back as fp32 pairs.
//
// Output layout (fp32 elements, concatenated in return order):
//   co : (B,H,L,L) = 25165824
//   w  : (B,L,1)   = 4096
//   Vh : (B,H,L,DH)= 3145728
#define CO_ELEMS 25165824
#define W_ELEMS  4096

// ws layout (fp32 elements), ~320 KB total:
#define OFF_Q2 0            // 24576
#define OFF_K2 24576        // 24576
#define OFF_WC 49152        // 24576  column sums (zero-init, atomic accum)
#define OFF_SP 73728        // 6144   per-block (sum, sumsq) partials
#define OFF_A1 79872        // 8
#define OFF_C1 79880        // 8

typedef __attribute__((ext_vector_type(8))) short short8;
typedef __attribute__((ext_vector_type(4))) float f32x4;

// load 8 contiguous fp32, truncate to bf16 fragment (error ~2^-9 relative;
// after batchnorm (sigma_S ~ 32) -> dz ~ 3e-3 -> co err ~ 3e-4 << 0.101 thr)
__device__ __forceinline__ short8 ld_bf8(const float* __restrict__ p) {
    const float4 a = *(const float4*)(p);
    const float4 b = *(const float4*)(p + 4);
    short8 r;
    r[0] = (short)(__float_as_uint(a.x) >> 16);
    r[1] = (short)(__float_as_uint(a.y) >> 16);
    r[2] = (short)(__float_as_uint(a.z) >> 16);
    r[3] = (short)(__float_as_uint(a.w) >> 16);
    r[4] = (short)(__float_as_uint(b.x) >> 16);
    r[5] = (short)(__float_as_uint(b.y) >> 16);
    r[6] = (short)(__float_as_uint(b.z) >> 16);
    r[7] = (short)(__float_as_uint(b.w) >> 16);
    return r;
}

// ----------------------------------------------- zero wcol (ws is 0xAA-poisoned)
__global__ void k_zero(float* __restrict__ wcol) {
    int g = blockIdx.x * 256 + threadIdx.x;
    if (g < 24576) wcol[g] = 0.0f;
}

// ------------------------------------------------- q2 / k2 (row sq-norms)
__global__ void k_rownorm(const float* __restrict__ Q,
                          const float* __restrict__ K,
                          float* __restrict__ ws) {
    int gid = blockIdx.x * 256 + threadIdx.x;       // 2 * 24576 * 4 = 196608
    int sub = gid & 3;
    int rg  = gid >> 2;                             // 0..49151
    int which = (rg >= 24576);
    int rid = which ? rg - 24576 : rg;              // bh*1024 + i
    int bh = rid >> 10, i = rid & 1023;
    int b = bh / HH, h = bh - b * HH;
    const float* src = (which ? K : Q) + (size_t)(b * LL + i) * DD + h * DHH;
    float s = 0.f;
#pragma unroll
    for (int kk = 0; kk < 8; kk++) {
        float4 v = *(const float4*)(src + (sub + 4 * kk) * 4);
        s += v.x * v.x + v.y * v.y + v.z * v.z + v.w * v.w;
    }
    s += __shfl_xor(s, 1);
    s += __shfl_xor(s, 2);
    if (sub == 0) ws[(which ? OFF_K2 : OFF_Q2) + rid] = s;
}

// ------------------------------------------------- Vh output (exact fp32 copy)
__global__ void k_vh(const float* __restrict__ V, float* __restrict__ out) {
    int cid = blockIdx.x * 256 + threadIdx.x;       // 786432 float4 chunks
    if (cid >= 786432) return;
    int d4 = cid & 31;                              // 32 float4 per (bh,l)
    int rest = cid >> 5;
    int l = rest & 1023;
    int bh = rest >> 10;
    int b = bh / HH, h = bh - b * HH;
    float4 v = *(const float4*)(V + (size_t)(b * LL + l) * DD + h * DHH + d4 * 4);
    *(float4*)(out + (size_t)cid * 4) = v;
}

// ------------------------------------------ shared QK^T MFMA tile helper
// wave tile 32x64 (2 x 4 of 16x16), block = 4 waves (2x2) -> 64x128 tile.
// C/D: col=lane&15, row=quad*4+reg   [verified m89/m91]
__device__ __forceinline__ void gemm_qk(const float* __restrict__ Qb,
                                        const float* __restrict__ Kb,
                                        int ibase, int jbase, int lm, int quad,
                                        f32x4 acc[2][4]) {
#pragma unroll
    for (int kk = 0; kk < 4; kk++) {
        const int d0 = kk * 32 + quad * 8;
        short8 af[2], bfr[4];
        af[0] = ld_bf8(Qb + (size_t)(ibase + lm) * DD + d0);
        af[1] = ld_bf8(Qb + (size_t)(ibase + 16 + lm) * DD + d0);
#pragma unroll
        for (int tj = 0; tj < 4; tj++)
            bfr[tj] = ld_bf8(Kb + (size_t)(jbase + tj * 16 + lm) * DD + d0);
#pragma unroll
        for (int ti = 0; ti < 2; ti++)
#pragma unroll
            for (int tj = 0; tj < 4; tj++)
                acc[ti][tj] = __builtin_amdgcn_mfma_f32_16x16x32_bf16(af[ti], bfr[tj], acc[ti][tj], 0, 0, 0);
    }
}

// -------------------------------------- pass 1: batchnorm stats of raw S
__global__ __launch_bounds__(256) void k_gemm_stats(
        const float* __restrict__ Q, const float* __restrict__ Km,
        const float* __restrict__ q2, const float* __restrict__ k2,
        float* __restrict__ statsP) {
    const int bh = blockIdx.z, b = bh / HH, h = bh - b * HH;
    const int tid = threadIdx.x, lane = tid & 63, wave = tid >> 6;
    const int wr = wave >> 1, wc = wave & 1;
    const int ibase = blockIdx.y * 64 + wr * 32;
    const int jbase = blockIdx.x * 128 + wc * 64;
    const int lm = lane & 15, quad = lane >> 4;
    const float* Qb = Q + (size_t)b * LL * DD + h * DHH;
    const float* Kb = Km + (size_t)b * LL * DD + h * DHH;

    f32x4 acc[2][4];
#pragma unroll
    for (int ti = 0; ti < 2; ti++)
#pragma unroll
        for (int tj = 0; tj < 4; tj++) acc[ti][tj] = (f32x4)(0.0f);
    gemm_qk(Qb, Kb, ibase, jbase, lm, quad, acc);

    float q2v[2][4], k2v[4];
#pragma unroll
    for (int ti = 0; ti < 2; ti++)
#pragma unroll
        for (int r = 0; r < 4; r++)
            q2v[ti][r] = q2[bh * 1024 + ibase + ti * 16 + quad * 4 + r];
#pragma unroll
    for (int tj = 0; tj < 4; tj++)
        k2v[tj] = k2[bh * 1024 + jbase + tj * 16 + lm];

    float s = 0.f, s2 = 0.f;
#pragma unroll
    for (int ti = 0; ti < 2; ti++)
#pragma unroll
        for (int tj = 0; tj < 4; tj++)
#pragma unroll
            for (int r = 0; r < 4; r++) {
                float S = 2.0f * acc[ti][tj][r] - q2v[ti][r] - k2v[tj];
                s += S; s2 += S * S;
            }

    __shared__ float rA[256], rB[256];
    rA[tid] = s; rB[tid] = s2;
    __syncthreads();
    for (int off = 128; off > 0; off >>= 1) {
        if (tid < off) { rA[tid] += rA[tid + off]; rB[tid] += rB[tid + off]; }
        __syncthreads();
    }
    if (tid == 0) {
        int blk = blockIdx.y * 8 + blockIdx.x;         // 0..127
        int base = (bh * 128 + blk) * 2;
        statsP[base] = rA[0];
        statsP[base + 1] = rB[0];
    }
}

// --------------------------------------------- reduce stats -> a,c per head
__global__ void k_stats(const float* __restrict__ statsP,
                        const float* __restrict__ g1, const float* __restrict__ b1,
                        float* __restrict__ a1, float* __restrict__ c1) {
    __shared__ float rA[256], rB[256];
    const int t = threadIdx.x;
    for (int h = 0; h < HH; h++) {
        float s = 0.f, s2 = 0.f;
        for (int m = t; m < 512; m += 256) {           // 4 batches * 128 blocks
            int b = m >> 7, blk = m & 127;
            int base = ((b * HH + h) * 128 + blk) * 2;
            s += statsP[base]; s2 += statsP[base + 1];
        }
        rA[t] = s; rB[t] = s2;
        __syncthreads();
        for (int off = 128; off > 0; off >>= 1) {
            if (t < off) { rA[t] += rA[t + off]; rB[t] += rB[t + off]; }
            __syncthreads();
        }
        if (t == 0) {
            const float N = 4194304.f;                 // 4*1024*1024
            float m_ = rA[0] / N;
            float var = fmaxf(rB[0] / N - m_ * m_, 0.0f);
            float r = rsqrtf(var + EPS);
            float a = r * g1[h];
            a1[h] = a;
            c1[h] = b1[h] - m_ * a;
        }
        __syncthreads();
    }
}

// ---- pass 2: co = exp(masked batchnorm(S))  (fp32, unnormalized)
__global__ __launch_bounds__(256) void k_gemm_exp(
        const float* __restrict__ Q, const float* __restrict__ Km,
        const float* __restrict__ q2, const float* __restrict__ k2,
        const float* __restrict__ a1, const float* __restrict__ c1,
        const unsigned char* __restrict__ bx,
        float* __restrict__ co) {
    const int bh = blockIdx.z, b = bh / HH, h = bh - b * HH;
    const int tid = threadIdx.x, lane = tid & 63, wave = tid >> 6;
    const int wr = wave >> 1, wc = wave & 1;
    const int ibase = blockIdx.y * 64 + wr * 32;
    const int jbase = blockIdx.x * 128 + wc * 64;
    const int lm = lane & 15, quad = lane >> 4;
    const float* Qb = Q + (size_t)b * LL * DD + h * DHH;
    const float* Kb = Km + (size_t)b * LL * DD + h * DHH;

    f32x4 acc[2][4];
#pragma unroll
    for (int ti = 0; ti < 2; ti++)
#pragma unroll
        for (int tj = 0; tj < 4; tj++) acc[ti][tj] = (f32x4)(0.0f);
    gemm_qk(Qb, Kb, ibase, jbase, lm, quad, acc);

    const float a = a1[h], c = c1[h];
    float q2v[2][4], k2v[4];
    bool vi[2][4], vj[4];
#pragma unroll
    for (int ti = 0; ti < 2; ti++)
#pragma unroll
        for (int r = 0; r < 4; r++) {
            int i = ibase + ti * 16 + quad * 4 + r;
            q2v[ti][r] = q2[bh * 1024 + i];
            vi[ti][r] = (bx[b * LL + i] == 0);
        }
#pragma unroll
    for (int tj = 0; tj < 4; tj++) {
        int j = jbase + tj * 16 + lm;
        k2v[tj] = k2[bh * 1024 + j];
        vj[tj] = (bx[b * LL + j] == 0);
    }

#pragma unroll
    for (int ti = 0; ti < 2; ti++)
#pragma unroll
        for (int tj = 0; tj < 4; tj++)
#pragma unroll
            for (int r = 0; r < 4; r++) {
                int i = ibase + ti * 16 + quad * 4 + r;
                int j = jbase + tj * 16 + lm;
                float S = 2.0f * acc[ti][tj][r] - q2v[ti][r] - k2v[tj];
                float y = a * S + c;
                float z = (vi[ti][r] && vj[tj]) ? y : 0.0f;  // masked_fill BEFORE softmax
                co[(size_t)(bh * 1024 + i) * 1024 + j] = __expf(fminf(z, 60.0f));
            }
}

// ---- pass 3: block owns 16 full rows x 1024 cols (coalesced float4):
// row sums from STORED values -> normalize in-register (p <= 1 by
// construction) -> write back; per-thread col sums -> 4 global atomicAdds.
__global__ __launch_bounds__(256) void k_norm(
        float* __restrict__ co, float* __restrict__ wcol) {
    const int bh = blockIdx.y;            // 24
    const int strip = blockIdx.x;         // 64 strips of 16 rows
    const int t = threadIdx.x;            // col group: cols 4t..4t+3
    float* base = co + ((size_t)bh << 20) + ((size_t)strip << 14);

    float4 buf[16];
    float rp[16];
#pragma unroll
    for (int r = 0; r < 16; r++) {
        buf[r] = *(const float4*)(base + r * 1024 + t * 4);
        rp[r] = buf[r].x + buf[r].y + buf[r].z + buf[r].w;
    }

    __shared__ float pr[16][257];
    __shared__ float pr2[16][17];
    __shared__ float inv[16];
#pragma unroll
    for (int r = 0; r < 16; r++) pr[r][t] = rp[r];
    __syncthreads();
    {
        int r = t >> 4, k = t & 15;
        float s = 0.f;
#pragma unroll
        for (int j = 0; j < 16; j++) s += pr[r][k * 16 + j];
        pr2[r][k] = s;
    }
    __syncthreads();
    if (t < 16) {
        float s = 0.f;
#pragma unroll
        for (int k = 0; k < 16; k++) s += pr2[t][k];
        inv[t] = 1.0f / s;
    }
    __syncthreads();

    float cs0 = 0.f, cs1 = 0.f, cs2 = 0.f, cs3 = 0.f;
#pragma unroll
    for (int r = 0; r < 16; r++) {
        const float iv = inv[r];
        float4 v = buf[r];
        v.x *= iv; v.y *= iv; v.z *= iv; v.w *= iv;
        *(float4*)(base + r * 1024 + t * 4) = v;
        cs0 += v.x; cs1 += v.y; cs2 += v.z; cs3 += v.w;
    }
    float* wc = wcol + bh * 1024 + t * 4;
    atomicAdd(wc + 0, cs0);
    atomicAdd(wc + 1, cs1);
    atomicAdd(wc + 2, cs2);
    atomicAdd(wc + 3, cs3);
}

// ------- tail: norm2 + posterior gate + final per-batch softmax -> w out
__global__ __launch_bounds__(1024) void k_tail(
        const float* __restrict__ wcol, const unsigned char* __restrict__ bx,
        const float* __restrict__ g2, const float* __restrict__ b2,
        const float* __restrict__ Wp, const float* __restrict__ bp,
        float* __restrict__ wout) {
    __shared__ float red[1024];
    __shared__ float red2[1024];
    __shared__ float a2s[HH], c2s[HH];
    __shared__ float xbuf[4096];
    const int t = threadIdx.x;

    for (int h = 0; h < HH; h++) {
        float s = 0.f, s2 = 0.f;
#pragma unroll
        for (int p = 0; p < 4; p++) {
            int idx = t + p * 1024;
            int b = idx >> 10, l = idx & 1023;
            float v = wcol[(size_t)(b * HH + h) * 1024 + l];
            s += v; s2 += v * v;
        }
        red[t] = s; red2[t] = s2;
        __syncthreads();
        for (int off = 512; off > 0; off >>= 1) {
            if (t < off) { red[t] += red[t + off]; red2[t] += red2[t + off]; }
            __syncthreads();
        }
        if (t == 0) {
            const float N = 4096.f;
            float m = red[0] / N;
            float var = fmaxf(red2[0] / N - m * m, 0.0f);
            float r = rsqrtf(var + EPS);
            float a = r * g2[h];
            a2s[h] = a;
            c2s[h] = b2[h] - m * a;
        }
        __syncthreads();
    }

    const float bp0 = bp[0], bp1 = bp[1];
#pragma unroll
    for (int p = 0; p < 4; p++) {
        int idx = t + p * 1024;
        int b = idx >> 10, l = idx & 1023;
        float z0 = bp0, z1 = bp1;
#pragma unroll
        for (int h = 0; h < HH; h++) {
            float wn = a2s[h] * wcol[(size_t)(b * HH + h) * 1024 + l] + c2s[h];
            z0 += wn * Wp[h];
            z1 += wn * Wp[HH + h];
        }
        float pc = 1.0f / (1.0f + __expf(z1 - z0));
        xbuf[idx] = bx[b * LL + l] ? -INFINITY : pc;
    }
    __syncthreads();

    for (int b = 0; b < BB; b++) {
        float x = xbuf[b * 1024 + t];
        red[t] = x;
        __syncthreads();
        for (int off = 512; off > 0; off >>= 1) {
            if (t < off) red[t] = fmaxf(red[t], red[t + off]);
            __syncthreads();
        }
        float mx = red[0];
        __syncthreads();
        float e = __expf(x - mx);          // exp(-inf) = 0 for padded
        red[t] = e;
        __syncthreads();
        for (int off = 512; off > 0; off >>= 1) {
            if (t < off) red[t] += red[t + off];
            __syncthreads();
        }
        float sum = red[0];
        __syncthreads();
        wout[b * 1024 + t] = e / sum;
    }
}

extern "C" void kernel_launch(void* const* d_in, const int* in_sizes, int n_in,
                              void* d_out, int out_size, void* d_ws, size_t ws_size,
                              hipStream_t stream) {
    const float* Q  = (const float*)d_in[0];
    const float* K  = (const float*)d_in[1];
    const float* V  = (const float*)d_in[2];
    // d_in[3] = pad_mask (B,L,L) — derivable from bx_packed, unused
    const unsigned char* bx = (const unsigned char*)d_in[4];
    const float* g1 = (const float*)d_in[5];
    const float* b1 = (const float*)d_in[6];
    const float* g2 = (const float*)d_in[7];
    const float* b2 = (const float*)d_in[8];
    const float* Wp = (const float*)d_in[9];
    const float* bp = (const float*)d_in[10];

    float* out  = (float*)d_out;
    float* co   = out;                        // (B,H,L,L)
    float* wout = out + CO_ELEMS;             // (B,L,1)
    float* vh   = out + CO_ELEMS + W_ELEMS;   // (B,H,L,DH)

    float* ws = (float*)d_ws;                 // ~320 KB
    float* q2     = ws + OFF_Q2;
    float* k2     = ws + OFF_K2;
    float* wcol   = ws + OFF_WC;
    float* statsP = ws + OFF_SP;
    float* a1     = ws + OFF_A1;
    float* c1     = ws + OFF_C1;

    k_zero<<<96, 256, 0, stream>>>(wcol);
    k_rownorm<<<768, 256, 0, stream>>>(Q, K, ws);
    k_vh<<<3072, 256, 0, stream>>>(V, vh);
    k_gemm_stats<<<dim3(8, 16, BB * HH), 256, 0, stream>>>(Q, K, q2, k2, statsP);
    k_stats<<<1, 256, 0, stream>>>(statsP, g1, b1, a1, c1);
    k_gemm_exp<<<dim3(8, 16, BB * HH), 256, 0, stream>>>(Q, K, q2, k2, a1, c1, bx, co);
    k_norm<<<dim3(64, 24), 256, 0, stream>>>(co, wcol);
    k_tail<<<1, 1024, 0, stream>>>(wcol, bx, g2, b2, Wp, bp, wout);
}

// Round 5
// 305.173 us; speedup vs baseline: 1.2046x; 1.2046x over previous
//
#include <hip/hip_runtime.h>
#include <stdint.h>
#include <stddef.h>

// Problem constants (B=4, L=1024, D=768, H=6, DH=128)
#define BB 4
#define LL 1024
#define DD 768
#define HH 6
#define DHH 128
#define EPS 1e-5f

// Inputs fp32, outputs fp32.
// Output layout (fp32 elements, concatenated in return order):
//   co : (B,H,L,L) = 25165824
//   w  : (B,L,1)   = 4096
//   Vh : (B,H,L,DH)= 3145728
#define CO_ELEMS 25165824
#define W_ELEMS  4096

// ws layout (fp32 elements), ~320 KB total:
#define OFF_Q2 0            // 24576
#define OFF_K2 24576        // 24576
#define OFF_WC 49152        // 24576  column sums (zero-init, atomic accum)
#define OFF_SP 73728        // 6144   per-block (sum, sumsq) partials
#define OFF_A1 79872        // 8
#define OFF_C1 79880        // 8

typedef __attribute__((ext_vector_type(8))) short short8;
typedef __attribute__((ext_vector_type(4))) float f32x4;

// load 8 contiguous fp32, truncate to bf16 fragment
__device__ __forceinline__ short8 ld_bf8(const float* __restrict__ p) {
    const float4 a = *(const float4*)(p);
    const float4 b = *(const float4*)(p + 4);
    short8 r;
    r[0] = (short)(__float_as_uint(a.x) >> 16);
    r[1] = (short)(__float_as_uint(a.y) >> 16);
    r[2] = (short)(__float_as_uint(a.z) >> 16);
    r[3] = (short)(__float_as_uint(a.w) >> 16);
    r[4] = (short)(__float_as_uint(b.x) >> 16);
    r[5] = (short)(__float_as_uint(b.y) >> 16);
    r[6] = (short)(__float_as_uint(b.z) >> 16);
    r[7] = (short)(__float_as_uint(b.w) >> 16);
    return r;
}

// ----------------------------------------------- zero wcol (ws is poisoned)
__global__ void k_zero(float* __restrict__ wcol) {
    int g = blockIdx.x * 256 + threadIdx.x;
    if (g < 24576) wcol[g] = 0.0f;
}

// ------------------------------------------------- q2 / k2 (row sq-norms)
__global__ void k_rownorm(const float* __restrict__ Q,
                          const float* __restrict__ K,
                          float* __restrict__ ws) {
    int gid = blockIdx.x * 256 + threadIdx.x;       // 2 * 24576 * 4 = 196608
    int sub = gid & 3;
    int rg  = gid >> 2;                             // 0..49151
    int which = (rg >= 24576);
    int rid = which ? rg - 24576 : rg;              // bh*1024 + i
    int bh = rid >> 10, i = rid & 1023;
    int b = bh / HH, h = bh - b * HH;
    const float* src = (which ? K : Q) + (size_t)(b * LL + i) * DD + h * DHH;
    float s = 0.f;
#pragma unroll
    for (int kk = 0; kk < 8; kk++) {
        float4 v = *(const float4*)(src + (sub + 4 * kk) * 4);
        s += v.x * v.x + v.y * v.y + v.z * v.z + v.w * v.w;
    }
    s += __shfl_xor(s, 1);
    s += __shfl_xor(s, 2);
    if (sub == 0) ws[(which ? OFF_K2 : OFF_Q2) + rid] = s;
}

// ------------------------------------------------- Vh output (exact fp32 copy)
__global__ void k_vh(const float* __restrict__ V, float* __restrict__ out) {
    int cid = blockIdx.x * 256 + threadIdx.x;       // 786432 float4 chunks
    if (cid >= 786432) return;
    int d4 = cid & 31;                              // 32 float4 per (bh,l)
    int rest = cid >> 5;
    int l = rest & 1023;
    int bh = rest >> 10;
    int b = bh / HH, h = bh - b * HH;
    float4 v = *(const float4*)(V + (size_t)(b * LL + l) * DD + h * DHH + d4 * 4);
    *(float4*)(out + (size_t)cid * 4) = v;
}

// ------------------------------------------ shared QK^T MFMA tile helper
// wave tile 32x64 (2 x 4 of 16x16), block = 4 waves (2x2) -> 64x128 tile.
// C/D: col=lane&15, row=quad*4+reg   [verified m89/m91]
__device__ __forceinline__ void gemm_qk(const float* __restrict__ Qb,
                                        const float* __restrict__ Kb,
                                        int ibase, int jbase, int lm, int quad,
                                        f32x4 acc[2][4]) {
#pragma unroll
    for (int kk = 0; kk < 4; kk++) {
        const int d0 = kk * 32 + quad * 8;
        short8 af[2], bfr[4];
        af[0] = ld_bf8(Qb + (size_t)(ibase + lm) * DD + d0);
        af[1] = ld_bf8(Qb + (size_t)(ibase + 16 + lm) * DD + d0);
#pragma unroll
        for (int tj = 0; tj < 4; tj++)
            bfr[tj] = ld_bf8(Kb + (size_t)(jbase + tj * 16 + lm) * DD + d0);
#pragma unroll
        for (int ti = 0; ti < 2; ti++)
#pragma unroll
            for (int tj = 0; tj < 4; tj++)
                acc[ti][tj] = __builtin_amdgcn_mfma_f32_16x16x32_bf16(af[ti], bfr[tj], acc[ti][tj], 0, 0, 0);
    }
}

// ---- single GEMM pass: write RAW S (fp32) to co AND accumulate BN partials
__global__ __launch_bounds__(256) void k_gemm_S(
        const float* __restrict__ Q, const float* __restrict__ Km,
        const float* __restrict__ q2, const float* __restrict__ k2,
        float* __restrict__ co, float* __restrict__ statsP) {
    const int bh = blockIdx.z, b = bh / HH, h = bh - b * HH;
    const int tid = threadIdx.x, lane = tid & 63, wave = tid >> 6;
    const int wr = wave >> 1, wc = wave & 1;
    const int ibase = blockIdx.y * 64 + wr * 32;
    const int jbase = blockIdx.x * 128 + wc * 64;
    const int lm = lane & 15, quad = lane >> 4;
    const float* Qb = Q + (size_t)b * LL * DD + h * DHH;
    const float* Kb = Km + (size_t)b * LL * DD + h * DHH;

    f32x4 acc[2][4];
#pragma unroll
    for (int ti = 0; ti < 2; ti++)
#pragma unroll
        for (int tj = 0; tj < 4; tj++) acc[ti][tj] = (f32x4)(0.0f);
    gemm_qk(Qb, Kb, ibase, jbase, lm, quad, acc);

    float q2v[2][4], k2v[4];
#pragma unroll
    for (int ti = 0; ti < 2; ti++)
#pragma unroll
        for (int r = 0; r < 4; r++)
            q2v[ti][r] = q2[bh * 1024 + ibase + ti * 16 + quad * 4 + r];
#pragma unroll
    for (int tj = 0; tj < 4; tj++)
        k2v[tj] = k2[bh * 1024 + jbase + tj * 16 + lm];

    float s = 0.f, s2 = 0.f;
#pragma unroll
    for (int ti = 0; ti < 2; ti++)
#pragma unroll
        for (int tj = 0; tj < 4; tj++)
#pragma unroll
            for (int r = 0; r < 4; r++) {
                int i = ibase + ti * 16 + quad * 4 + r;
                int j = jbase + tj * 16 + lm;
                float S = 2.0f * acc[ti][tj][r] - q2v[ti][r] - k2v[tj];
                co[(size_t)(bh * 1024 + i) * 1024 + j] = S;
                s += S; s2 += S * S;
            }

    __shared__ float rA[256], rB[256];
    rA[tid] = s; rB[tid] = s2;
    __syncthreads();
    for (int off = 128; off > 0; off >>= 1) {
        if (tid < off) { rA[tid] += rA[tid + off]; rB[tid] += rB[tid + off]; }
        __syncthreads();
    }
    if (tid == 0) {
        int blk = blockIdx.y * 8 + blockIdx.x;         // 0..127
        int base = (bh * 128 + blk) * 2;
        statsP[base] = rA[0];
        statsP[base + 1] = rB[0];
    }
}

// --------------------------------------------- reduce stats -> a,c per head
__global__ void k_stats(const float* __restrict__ statsP,
                        const float* __restrict__ g1, const float* __restrict__ b1,
                        float* __restrict__ a1, float* __restrict__ c1) {
    __shared__ float rA[256], rB[256];
    const int t = threadIdx.x;
    for (int h = 0; h < HH; h++) {
        float s = 0.f, s2 = 0.f;
        for (int m = t; m < 512; m += 256) {           // 4 batches * 128 blocks
            int b = m >> 7, blk = m & 127;
            int base = ((b * HH + h) * 128 + blk) * 2;
            s += statsP[base]; s2 += statsP[base + 1];
        }
        rA[t] = s; rB[t] = s2;
        __syncthreads();
        for (int off = 128; off > 0; off >>= 1) {
            if (t < off) { rA[t] += rA[t + off]; rB[t] += rB[t + off]; }
            __syncthreads();
        }
        if (t == 0) {
            const float N = 4194304.f;                 // 4*1024*1024
            float m_ = rA[0] / N;
            float var = fmaxf(rB[0] / N - m_ * m_, 0.0f);
            float r = rsqrtf(var + EPS);
            float a = r * g1[h];
            a1[h] = a;
            c1[h] = b1[h] - m_ * a;
        }
        __syncthreads();
    }
}

// ---- fused pass: read S, e = exp(masked BN(S)), row-softmax in-block
// (block owns 16 full rows, coalesced float4), write p, col-sum atomics.
__global__ __launch_bounds__(256) void k_normexp(
        float* __restrict__ co,
        const float* __restrict__ a1, const float* __restrict__ c1,
        const unsigned char* __restrict__ bx, float* __restrict__ wcol) {
    const int bh = blockIdx.y;            // 24
    const int b = bh / HH, h = bh - b * HH;
    const int strip = blockIdx.x;         // 64 strips of 16 rows
    const int t = threadIdx.x;            // col group: cols 4t..4t+3
    float* base = co + ((size_t)bh << 20) + ((size_t)strip << 14);
    const float a = a1[h], c = c1[h];

    // col validity for this thread's 4 cols
    const unsigned char* bxb = bx + b * LL;
    const uchar4 m4 = *(const uchar4*)(bxb + t * 4);
    const bool vj0 = (m4.x == 0), vj1 = (m4.y == 0), vj2 = (m4.z == 0), vj3 = (m4.w == 0);

    float4 buf[16];
    float rp[16];
#pragma unroll
    for (int r = 0; r < 16; r++) {
        const int i = strip * 16 + r;
        const bool vi = (bxb[i] == 0);
        float4 s4 = *(const float4*)(base + r * 1024 + t * 4);
        float4 e;
        e.x = (vi && vj0) ? __expf(fminf(a * s4.x + c, 60.0f)) : 1.0f;
        e.y = (vi && vj1) ? __expf(fminf(a * s4.y + c, 60.0f)) : 1.0f;
        e.z = (vi && vj2) ? __expf(fminf(a * s4.z + c, 60.0f)) : 1.0f;
        e.w = (vi && vj3) ? __expf(fminf(a * s4.w + c, 60.0f)) : 1.0f;
        buf[r] = e;
        rp[r] = e.x + e.y + e.z + e.w;
    }

    __shared__ float pr[16][257];
    __shared__ float pr2[16][17];
    __shared__ float inv[16];
#pragma unroll
    for (int r = 0; r < 16; r++) pr[r][t] = rp[r];
    __syncthreads();
    {
        int r = t >> 4, k = t & 15;
        float s = 0.f;
#pragma unroll
        for (int j = 0; j < 16; j++) s += pr[r][k * 16 + j];
        pr2[r][k] = s;
    }
    __syncthreads();
    if (t < 16) {
        float s = 0.f;
#pragma unroll
        for (int k = 0; k < 16; k++) s += pr2[t][k];
        inv[t] = 1.0f / s;
    }
    __syncthreads();

    float cs0 = 0.f, cs1 = 0.f, cs2 = 0.f, cs3 = 0.f;
#pragma unroll
    for (int r = 0; r < 16; r++) {
        const float iv = inv[r];
        float4 v = buf[r];
        v.x *= iv; v.y *= iv; v.z *= iv; v.w *= iv;
        *(float4*)(base + r * 1024 + t * 4) = v;
        cs0 += v.x; cs1 += v.y; cs2 += v.z; cs3 += v.w;
    }
    float* wc = wcol + bh * 1024 + t * 4;
    atomicAdd(wc + 0, cs0);
    atomicAdd(wc + 1, cs1);
    atomicAdd(wc + 2, cs2);
    atomicAdd(wc + 3, cs3);
}

// ------- tail: norm2 + posterior gate + final per-batch softmax -> w out
__global__ __launch_bounds__(1024) void k_tail(
        const float* __restrict__ wcol, const unsigned char* __restrict__ bx,
        const float* __restrict__ g2, const float* __restrict__ b2,
        const float* __restrict__ Wp, const float* __restrict__ bp,
        float* __restrict__ wout) {
    __shared__ float red[1024];
    __shared__ float red2[1024];
    __shared__ float a2s[HH], c2s[HH];
    __shared__ float xbuf[4096];
    const int t = threadIdx.x;

    for (int h = 0; h < HH; h++) {
        float s = 0.f, s2 = 0.f;
#pragma unroll
        for (int p = 0; p < 4; p++) {
            int idx = t + p * 1024;
            int b = idx >> 10, l = idx & 1023;
            float v = wcol[(size_t)(b * HH + h) * 1024 + l];
            s += v; s2 += v * v;
        }
        red[t] = s; red2[t] = s2;
        __syncthreads();
        for (int off = 512; off > 0; off >>= 1) {
            if (t < off) { red[t] += red[t + off]; red2[t] += red2[t + off]; }
            __syncthreads();
        }
        if (t == 0) {
            const float N = 4096.f;
            float m = red[0] / N;
            float var = fmaxf(red2[0] / N - m * m, 0.0f);
            float r = rsqrtf(var + EPS);
            float a = r * g2[h];
            a2s[h] = a;
            c2s[h] = b2[h] - m * a;
        }
        __syncthreads();
    }

    const float bp0 = bp[0], bp1 = bp[1];
#pragma unroll
    for (int p = 0; p < 4; p++) {
        int idx = t + p * 1024;
        int b = idx >> 10, l = idx & 1023;
        float z0 = bp0, z1 = bp1;
#pragma unroll
        for (int h = 0; h < HH; h++) {
            float wn = a2s[h] * wcol[(size_t)(b * HH + h) * 1024 + l] + c2s[h];
            z0 += wn * Wp[h];
            z1 += wn * Wp[HH + h];
        }
        float pc = 1.0f / (1.0f + __expf(z1 - z0));
        xbuf[idx] = bx[b * LL + l] ? -INFINITY : pc;
    }
    __syncthreads();

    for (int b = 0; b < BB; b++) {
        float x = xbuf[b * 1024 + t];
        red[t] = x;
        __syncthreads();
        for (int off = 512; off > 0; off >>= 1) {
            if (t < off) red[t] = fmaxf(red[t], red[t + off]);
            __syncthreads();
        }
        float mx = red[0];
        __syncthreads();
        float e = __expf(x - mx);          // exp(-inf) = 0 for padded
        red[t] = e;
        __syncthreads();
        for (int off = 512; off > 0; off >>= 1) {
            if (t < off) red[t] += red[t + off];
            __syncthreads();
        }
        float sum = red[0];
        __syncthreads();
        wout[b * 1024 + t] = e / sum;
    }
}

extern "C" void kernel_launch(void* const* d_in, const int* in_sizes, int n_in,
                              void* d_out, int out_size, void* d_ws, size_t ws_size,
                              hipStream_t stream) {
    const float* Q  = (const float*)d_in[0];
    const float* K  = (const float*)d_in[1];
    const float* V  = (const float*)d_in[2];
    // d_in[3] = pad_mask (B,L,L) — derivable from bx_packed, unused
    const unsigned char* bx = (const unsigned char*)d_in[4];
    const float* g1 = (const float*)d_in[5];
    const float* b1 = (const float*)d_in[6];
    const float* g2 = (const float*)d_in[7];
    const float* b2 = (const float*)d_in[8];
    const float* Wp = (const float*)d_in[9];
    const float* bp = (const float*)d_in[10];

    float* out  = (float*)d_out;
    float* co   = out;                        // (B,H,L,L)
    float* wout = out + CO_ELEMS;             // (B,L,1)
    float* vh   = out + CO_ELEMS + W_ELEMS;   // (B,H,L,DH)

    float* ws = (float*)d_ws;                 // ~320 KB
    float* q2     = ws + OFF_Q2;
    float* k2     = ws + OFF_K2;
    float* wcol   = ws + OFF_WC;
    float* statsP = ws + OFF_SP;
    float* a1     = ws + OFF_A1;
    float* c1     = ws + OFF_C1;

    k_zero<<<96, 256, 0, stream>>>(wcol);
    k_rownorm<<<768, 256, 0, stream>>>(Q, K, ws);
    k_vh<<<3072, 256, 0, stream>>>(V, vh);
    k_gemm_S<<<dim3(8, 16, BB * HH), 256, 0, stream>>>(Q, K, q2, k2, co, statsP);
    k_stats<<<1, 256, 0, stream>>>(statsP, g1, b1, a1, c1);
    k_normexp<<<dim3(64, 24), 256, 0, stream>>>(co, a1, c1, bx, wcol);
    k_tail<<<1, 1024, 0, stream>>>(wcol, bx, g2, b2, Wp, bp, wout);
}